// Round 1
// 254.825 us; speedup vs baseline: 1.0783x; 1.0783x over previous
//
#include <hip/hip_runtime.h>

// Skewed MAE: mean(|p - t| * exp(sign(t - p) * (2t - 1)))
//
// R3 probe: identical structure to R2's two-stage kernel; ONLY change is
// non-temporal (MUBUF nt) loads for both input streams.
// Theory: inputs are freshly rewritten by the harness restore each
// iteration and sit dirty in the 256MB Infinity Cache; traffic served
// through the L3 allocate path ceilings at ~2.7 TB/s (268MB / 100us),
// which matches R2's "dur invariant to residency" observation. nt loads
// (no-allocate / evict-first in L2+MALL) should let the HBM-miss half
// stream at full rate in parallel with the L3 dirty-hit half.
// Prediction: stage1 100us -> 55-70us if theory right; unchanged if the
// ceiling is the XCD fabric; WRITE_SIZE blowup = nt forcing writebacks.

#define BLOCK 256
#define GRID 2048
#define UNROLL 8

typedef float f32x4 __attribute__((ext_vector_type(4)));

__device__ __forceinline__ float skew_elem(float p, float t) {
    float d = p - t;
    float lam = __builtin_fmaf(2.0f, t, -1.0f);     // 2t - 1
    float s = (d < 0.0f) ? lam : -lam;              // sign(t-p)*lam; d==0 -> |d|=0
    return fabsf(d) * __expf(s);
}

__device__ __forceinline__ float block_reduce(float acc) {
    #pragma unroll
    for (int off = 32; off > 0; off >>= 1)
        acc += __shfl_down(acc, off, 64);
    __shared__ float smem[BLOCK / 64];
    int lane = threadIdx.x & 63;
    int wave = threadIdx.x >> 6;
    if (lane == 0) smem[wave] = acc;
    __syncthreads();
    float s = 0.0f;
    #pragma unroll
    for (int w = 0; w < BLOCK / 64; ++w) s += smem[w];
    return s;   // valid in all threads (cheap; avoids a second sync)
}

__global__ __launch_bounds__(BLOCK) void skewed_mae_stage1(
        const f32x4* __restrict__ yp4, const f32x4* __restrict__ yt4,
        const float* __restrict__ yp, const float* __restrict__ yt,
        float* __restrict__ partials, int n4, int n, float inv_n) {
    const int tid = blockIdx.x * BLOCK + threadIdx.x;
    const int stride = GRID * BLOCK;

    float acc = 0.0f;

    int base = tid;
    for (; base + (UNROLL - 1) * stride < n4; base += UNROLL * stride) {
        f32x4 p[UNROLL], t[UNROLL];
        #pragma unroll
        for (int k = 0; k < UNROLL; ++k)
            p[k] = __builtin_nontemporal_load(yp4 + base + k * stride);
        #pragma unroll
        for (int k = 0; k < UNROLL; ++k)
            t[k] = __builtin_nontemporal_load(yt4 + base + k * stride);
        #pragma unroll
        for (int k = 0; k < UNROLL; ++k) {
            acc += skew_elem(p[k].x, t[k].x);
            acc += skew_elem(p[k].y, t[k].y);
            acc += skew_elem(p[k].z, t[k].z);
            acc += skew_elem(p[k].w, t[k].w);
        }
    }
    for (; base < n4; base += stride) {
        f32x4 p = __builtin_nontemporal_load(yp4 + base);
        f32x4 t = __builtin_nontemporal_load(yt4 + base);
        acc += skew_elem(p.x, t.x);
        acc += skew_elem(p.y, t.y);
        acc += skew_elem(p.z, t.z);
        acc += skew_elem(p.w, t.w);
    }
    for (int i = n4 * 4 + tid; i < n; i += stride) {
        acc += skew_elem(yp[i], yt[i]);
    }
    acc *= inv_n;

    float s = block_reduce(acc);
    if (threadIdx.x == 0) partials[blockIdx.x] = s;
}

// Stage 2: one block reduces GRID partials and writes the scalar output.
__global__ __launch_bounds__(BLOCK) void skewed_mae_stage2(
        const float* __restrict__ partials, float* __restrict__ out) {
    float acc = 0.0f;
    #pragma unroll
    for (int k = 0; k < GRID / BLOCK; ++k)
        acc += partials[k * BLOCK + threadIdx.x];
    float s = block_reduce(acc);
    if (threadIdx.x == 0) out[0] = s;
}

extern "C" void kernel_launch(void* const* d_in, const int* in_sizes, int n_in,
                              void* d_out, int out_size, void* d_ws, size_t ws_size,
                              hipStream_t stream) {
    const float* yp = (const float*)d_in[0];
    const float* yt = (const float*)d_in[1];
    float* out = (float*)d_out;
    float* partials = (float*)d_ws;    // GRID floats = 8 KB scratch
    int n = in_sizes[0];
    int n4 = n / 4;

    skewed_mae_stage1<<<GRID, BLOCK, 0, stream>>>(
        (const f32x4*)yp, (const f32x4*)yt, yp, yt, partials, n4, n,
        1.0f / (float)n);
    skewed_mae_stage2<<<1, BLOCK, 0, stream>>>(partials, out);
}

// Round 2
// 252.852 us; speedup vs baseline: 1.0867x; 1.0078x over previous
//
#include <hip/hip_runtime.h>

// Skewed MAE: mean(|p - t| * exp(sign(t - p) * (2t - 1)))
//
// R4: attack read MLP. R3 post-mortem: nt loads gave -20us (stage1 ~100->80us,
// 3.35 TB/s read). fillBuffer proves the memory system does 6.9 TB/s
// one-directional; stage1's VGPR_Count=12 proves the compiler sank every load
// next to its use (12 regs can't hold one batch), serializing to ~1-2
// outstanding loads/wave. Fix: sched_barrier(0) fence between load batch and
// compute batch forces all 8 loads in flight; UNROLL 4 keeps VGPR<=64 so
// launch_bounds(256,8) holds 8 blocks/CU and GRID=2048 stays exactly resident.
// Predict: VGPR ~48-64, stage1 -> 50-65us, total -> 225-240us.
// Null result => pure-read path ceiling ~3.3 TB/s confirmed.

#define BLOCK 256
#define GRID 2048
#define UNROLL 4

typedef float f32x4 __attribute__((ext_vector_type(4)));

__device__ __forceinline__ float skew_elem(float p, float t) {
    float d = p - t;
    float lam = __builtin_fmaf(2.0f, t, -1.0f);     // 2t - 1
    float s = (d < 0.0f) ? lam : -lam;              // sign(t-p)*lam; d==0 -> |d|=0
    return fabsf(d) * __expf(s);
}

__device__ __forceinline__ float block_reduce(float acc) {
    #pragma unroll
    for (int off = 32; off > 0; off >>= 1)
        acc += __shfl_down(acc, off, 64);
    __shared__ float smem[BLOCK / 64];
    int lane = threadIdx.x & 63;
    int wave = threadIdx.x >> 6;
    if (lane == 0) smem[wave] = acc;
    __syncthreads();
    float s = 0.0f;
    #pragma unroll
    for (int w = 0; w < BLOCK / 64; ++w) s += smem[w];
    return s;   // valid in all threads (cheap; avoids a second sync)
}

__global__ __launch_bounds__(BLOCK, 8) void skewed_mae_stage1(
        const f32x4* __restrict__ yp4, const f32x4* __restrict__ yt4,
        const float* __restrict__ yp, const float* __restrict__ yt,
        float* __restrict__ partials, int n4, int n, float inv_n) {
    const int tid = blockIdx.x * BLOCK + threadIdx.x;
    const int stride = GRID * BLOCK;

    float acc = 0.0f;

    int base = tid;
    for (; base + (UNROLL - 1) * stride < n4; base += UNROLL * stride) {
        f32x4 p[UNROLL], t[UNROLL];
        // Interleaved issue: first-consumed pair lands first; 8 loads in
        // flight before any consume.
        #pragma unroll
        for (int k = 0; k < UNROLL; ++k) {
            p[k] = __builtin_nontemporal_load(yp4 + base + k * stride);
            t[k] = __builtin_nontemporal_load(yt4 + base + k * stride);
        }
        // Scheduling fence: loads may NOT sink past this point, compute may
        // not hoist above it. Forces the full batch outstanding.
        __builtin_amdgcn_sched_barrier(0);
        #pragma unroll
        for (int k = 0; k < UNROLL; ++k) {
            acc += skew_elem(p[k].x, t[k].x);
            acc += skew_elem(p[k].y, t[k].y);
            acc += skew_elem(p[k].z, t[k].z);
            acc += skew_elem(p[k].w, t[k].w);
        }
    }
    for (; base < n4; base += stride) {
        f32x4 p = __builtin_nontemporal_load(yp4 + base);
        f32x4 t = __builtin_nontemporal_load(yt4 + base);
        acc += skew_elem(p.x, t.x);
        acc += skew_elem(p.y, t.y);
        acc += skew_elem(p.z, t.z);
        acc += skew_elem(p.w, t.w);
    }
    for (int i = n4 * 4 + tid; i < n; i += stride) {
        acc += skew_elem(yp[i], yt[i]);
    }
    acc *= inv_n;

    float s = block_reduce(acc);
    if (threadIdx.x == 0) partials[blockIdx.x] = s;
}

// Stage 2: one block reduces GRID partials and writes the scalar output.
__global__ __launch_bounds__(BLOCK) void skewed_mae_stage2(
        const float* __restrict__ partials, float* __restrict__ out) {
    float acc = 0.0f;
    #pragma unroll
    for (int k = 0; k < GRID / BLOCK; ++k)
        acc += partials[k * BLOCK + threadIdx.x];
    float s = block_reduce(acc);
    if (threadIdx.x == 0) out[0] = s;
}

extern "C" void kernel_launch(void* const* d_in, const int* in_sizes, int n_in,
                              void* d_out, int out_size, void* d_ws, size_t ws_size,
                              hipStream_t stream) {
    const float* yp = (const float*)d_in[0];
    const float* yt = (const float*)d_in[1];
    float* out = (float*)d_out;
    float* partials = (float*)d_ws;    // GRID floats = 8 KB scratch
    int n = in_sizes[0];
    int n4 = n / 4;

    skewed_mae_stage1<<<GRID, BLOCK, 0, stream>>>(
        (const f32x4*)yp, (const f32x4*)yt, yp, yt, partials, n4, n,
        1.0f / (float)n);
    skewed_mae_stage2<<<1, BLOCK, 0, stream>>>(partials, out);
}